// Round 1
// baseline (2413.371 us; speedup 1.0000x reference)
//
#include <hip/hip_runtime.h>

#define NB 8
#define NH 512
#define NW 640
#define NHW (NH*NW)
#define NBHW (NB*NHW)
#define TOPK 512
#define CAP 40960
#define PAD 8

// Gaussian taps exp(-d^2/(2*0.5^2)) = exp(-2 d^2), unnormalized (matches outer(g1,g1))
__constant__ float GK[8] = {
  1.0f,
  0.1353352832366127f,
  3.3546262790251185e-4f,
  1.5229979744712628e-8f,
  1.2664165549094176e-14f,
  1.928749847963918e-22f,
  5.380186160021138e-32f,
  2.7487850079102147e-43f
};

__device__ __forceinline__ float bordered(const float* __restrict__ img, int b, int y, int x) {
  if (y < PAD || y >= NH - PAD || x < PAD || x >= NW - PAD) return 0.f;
  return img[b * NHW + y * NW + x];
}

__device__ __forceinline__ void corner(const float* __restrict__ img, float cx, float cy,
                                       float wgt, float& acc, float& vacc) {
  float valid = (cx >= 0.f && cx <= (float)(NW - 1) && cy >= 0.f && cy <= (float)(NH - 1)) ? 1.f : 0.f;
  float xc = fminf(fmaxf(cx, 0.f), (float)(NW - 1));
  float yc = fminf(fmaxf(cy, 0.f), (float)(NH - 1));
  int xi = (int)xc, yi = (int)yc;
  float g = img[yi * NW + xi] * valid;
  acc += wgt * g;
  vacc += wgt * valid;
}

// Pass 1: warp score2 by homo, border-filter -> w2; visibility mask -> vis
__global__ void k_warp(const float* __restrict__ score2, const float* __restrict__ homo,
                       float* __restrict__ w2, float* __restrict__ vis) {
  int gid = blockIdx.x * blockDim.x + threadIdx.x;
  if (gid >= NBHW) return;
  int b = gid / NHW;
  int p = gid % NHW;
  int y = p / NW, x = p % NW;
  const float* hm = homo + b * 9;
  float xf = (float)x, yf = (float)y;
  float X = hm[0] * xf + hm[1] * yf + hm[2];
  float Y = hm[3] * xf + hm[4] * yf + hm[5];
  float Z = hm[6] * xf + hm[7] * yf + hm[8];
  float x2 = X / Z, y2 = Y / Z;
  float x0 = floorf(x2), y0 = floorf(y2);
  float x1 = x0 + 1.f, y1 = y0 + 1.f;
  float wa = (x1 - x2) * (y1 - y2);
  float wb = (x2 - x0) * (y1 - y2);
  float wc = (x1 - x2) * (y2 - y0);
  float wd = (x2 - x0) * (y2 - y0);
  const float* img = score2 + b * NHW;
  float acc = 0.f, vacc = 0.f;
  corner(img, x0, y0, wa, acc, vacc);
  corner(img, x1, y0, wb, acc, vacc);
  corner(img, x0, y1, wc, acc, vacc);
  corner(img, x1, y1, wd, acc, vacc);
  bool inb = (y >= PAD && y < NH - PAD && x >= PAD && x < NW - PAD);
  w2[gid] = inb ? acc : 0.f;
  vis[gid] = (vacc > 0.f) ? 1.f : 0.f;
}

// Pass 2: 5x5 NMS on border-filtered image; survivors pushed as 64-bit keys
// key = (float_bits(val) << 32) | ~idx  -> descending key order == (val desc, idx asc)
__global__ void k_nms(const float* __restrict__ score1, const float* __restrict__ w2,
                      unsigned long long* __restrict__ lists, unsigned int* __restrict__ cnts) {
  int gid = blockIdx.x * blockDim.x + threadIdx.x;
  if (gid >= NBHW) return;
  int src = blockIdx.y;
  const float* img = (src == 0) ? score1 : w2;
  int b = gid / NHW;
  int p = gid % NHW;
  int y = p / NW, x = p % NW;
  float val = bordered(img, b, y, x);
  if (val <= 0.f) return;  // NMS_THRESH = 0
  float m = val;
  #pragma unroll
  for (int dy = -2; dy <= 2; ++dy) {
    #pragma unroll
    for (int dx = -2; dx <= 2; ++dx) {
      int yy = y + dy, xx = x + dx;
      if (yy < 0 || yy >= NH || xx < 0 || xx >= NW) continue;
      m = fmaxf(m, bordered(img, b, yy, xx));
    }
  }
  if (m == val) {
    int li = src * NB + b;
    unsigned int pos = atomicAdd(&cnts[li], 1u);
    if (pos < CAP) {
      unsigned long long key = ((unsigned long long)__float_as_uint(val) << 32)
                             | (unsigned long long)(~(unsigned int)p);
      lists[(size_t)li * CAP + pos] = key;
    }
  }
}

// Pass 3: exact top-512 per (source,image) via 64-bit MSB radix select + bitonic sort.
// src 0 -> write kp1 to out; src 1 -> scatter values into sel.
__global__ __launch_bounds__(1024) void k_topk(const unsigned long long* __restrict__ lists,
                                               const unsigned int* __restrict__ cnts,
                                               float* __restrict__ out, float* __restrict__ sel) {
  int li = blockIdx.x;           // 0..15
  int src = li >> 3, b = li & 7;
  unsigned int N = cnts[li]; if (N > CAP) N = CAP;
  const unsigned long long* list = lists + (size_t)li * CAP;
  __shared__ unsigned int hist[256];
  __shared__ unsigned long long keys[TOPK];
  __shared__ unsigned int scnt;
  __shared__ unsigned long long s_prefix;
  __shared__ int s_remaining;
  int tid = threadIdx.x, nt = blockDim.x;
  if (tid == 0) { s_prefix = 0ULL; s_remaining = TOPK; scnt = 0; }
  __syncthreads();

  unsigned long long threshold = 0ULL;
  if (N > TOPK) {
    for (int byte = 7; byte >= 0; --byte) {
      for (int i = tid; i < 256; i += nt) hist[i] = 0;
      __syncthreads();
      unsigned long long prefix = s_prefix;
      unsigned long long maskHigh = (byte == 7) ? 0ULL : (~0ULL << (unsigned)((byte + 1) * 8));
      int shift = byte * 8;
      for (unsigned int i = tid; i < N; i += nt) {
        unsigned long long k = list[i];
        if ((k & maskHigh) == prefix)
          atomicAdd(&hist[(unsigned int)(k >> shift) & 0xFFu], 1u);
      }
      __syncthreads();
      if (tid == 0) {
        int rem = s_remaining;
        unsigned int cum = 0;
        int chosen = 0;
        for (int bin = 255; bin >= 0; --bin) {
          unsigned int c = hist[bin];
          if (cum + c >= (unsigned int)rem) { chosen = bin; s_remaining = rem - (int)cum; break; }
          cum += c;
        }
        s_prefix = prefix | ((unsigned long long)chosen << shift);
      }
      __syncthreads();
    }
    threshold = s_prefix;
  }

  // collect keys >= threshold (exactly TOPK when N > TOPK; keys are unique)
  for (unsigned int i = tid; i < N; i += nt) {
    unsigned long long k = list[i];
    if (k >= threshold) {
      unsigned int pos = atomicAdd(&scnt, 1u);
      if (pos < TOPK) keys[pos] = k;
    }
  }
  __syncthreads();
  unsigned int M = scnt; if (M > TOPK) M = TOPK;
  for (unsigned int i = M + tid; i < TOPK; i += nt) keys[i] = 0ULL;
  __syncthreads();

  // bitonic sort descending, 512 elements
  for (int k2 = 2; k2 <= TOPK; k2 <<= 1) {
    for (int j = k2 >> 1; j > 0; j >>= 1) {
      for (int i = tid; i < TOPK; i += nt) {
        int ixj = i ^ j;
        if (ixj > i) {
          bool desc = ((i & k2) == 0);
          unsigned long long a = keys[i], c = keys[ixj];
          bool sw = desc ? (a < c) : (a > c);
          if (sw) { keys[i] = c; keys[ixj] = a; }
        }
      }
      __syncthreads();
    }
  }

  if (src == 0) {
    for (int r = tid; r < TOPK; r += nt) {
      unsigned long long k = keys[r];
      unsigned int idx = (k == 0ULL) ? 0u : ~(unsigned int)(k & 0xFFFFFFFFu);
      int yy = (int)(idx / NW), xx = (int)(idx % NW);
      out[1 + ((b * TOPK) + r) * 2 + 0] = (float)yy;
      out[1 + ((b * TOPK) + r) * 2 + 1] = (float)xx;
    }
  } else {
    for (unsigned int r = tid; r < M; r += nt) {
      unsigned long long k = keys[r];
      unsigned int idx = ~(unsigned int)(k & 0xFFFFFFFFu);
      sel[b * NHW + idx] = __uint_as_float((unsigned int)(k >> 32));
    }
  }
}

// Pass 4a: horizontal gaussian blur sel -> tmp
__global__ void k_blur_row(const float* __restrict__ sel, float* __restrict__ tmp) {
  int gid = blockIdx.x * blockDim.x + threadIdx.x;
  if (gid >= NBHW) return;
  int b = gid / NHW;
  int p = gid % NHW;
  int y = p / NW, x = p % NW;
  const float* row = sel + b * NHW + y * NW;
  float acc = 0.f;
  #pragma unroll
  for (int d = -7; d <= 7; ++d) {
    int xx = x + d;
    if (xx >= 0 && xx < NW) acc += GK[d < 0 ? -d : d] * row[xx];
  }
  tmp[gid] = acc;
}

// Pass 4b: vertical blur (gt) + masked squared-error partial sums
__global__ void k_loss(const float* __restrict__ score1, const float* __restrict__ tmp,
                       const float* __restrict__ vis, float* __restrict__ partials) {
  int gid = blockIdx.x * blockDim.x + threadIdx.x;
  float term = 0.f, vsum = 0.f;
  if (gid < NBHW) {
    int b = gid / NHW;
    int p = gid % NHW;
    int y = p / NW, x = p % NW;
    float gt = 0.f;
    #pragma unroll
    for (int d = -7; d <= 7; ++d) {
      int yy = y + d;
      if (yy >= 0 && yy < NH) gt += GK[d < 0 ? -d : d] * tmp[b * NHW + yy * NW + x];
    }
    float s1v = bordered(score1, b, y, x);
    float v = vis[gid];
    float df = s1v - gt;
    term = df * df * v;
    vsum = v;
  }
  __shared__ float shA[256];
  __shared__ float shB[256];
  int tid = threadIdx.x;
  shA[tid] = term; shB[tid] = vsum;
  __syncthreads();
  for (int s = 128; s > 0; s >>= 1) {
    if (tid < s) { shA[tid] += shA[tid + s]; shB[tid] += shB[tid + s]; }
    __syncthreads();
  }
  if (tid == 0) {
    partials[2 * blockIdx.x + 0] = shA[0];
    partials[2 * blockIdx.x + 1] = shB[0];
  }
}

// Pass 5: final deterministic reduction -> loss
__global__ void k_final(const float* __restrict__ partials, int np, float* __restrict__ out) {
  __shared__ double dA[256];
  __shared__ double dB[256];
  int tid = threadIdx.x;
  double s = 0.0, n = 0.0;
  for (int i = tid; i < np; i += 256) {
    s += (double)partials[2 * i + 0];
    n += (double)partials[2 * i + 1];
  }
  dA[tid] = s; dB[tid] = n;
  __syncthreads();
  for (int st = 128; st > 0; st >>= 1) {
    if (tid < st) { dA[tid] += dA[tid + st]; dB[tid] += dB[tid + st]; }
    __syncthreads();
  }
  if (tid == 0) out[0] = (float)(100.0 * dA[0] / dB[0]);
}

extern "C" void kernel_launch(void* const* d_in, const int* in_sizes, int n_in,
                              void* d_out, int out_size, void* d_ws, size_t ws_size,
                              hipStream_t stream) {
  const float* score1 = (const float*)d_in[0];
  const float* score2 = (const float*)d_in[1];
  const float* homo   = (const float*)d_in[2];
  float* out = (float*)d_out;

  // workspace layout
  float* w2buf  = (float*)d_ws;
  float* visbuf = w2buf + NBHW;
  float* selbuf = visbuf + NBHW;
  float* tmpbuf = selbuf + NBHW;
  unsigned long long* lists = (unsigned long long*)(tmpbuf + NBHW);
  unsigned int* cnts = (unsigned int*)(lists + (size_t)16 * CAP);
  float* partials = (float*)(cnts + 16);

  const int nb = NBHW / 256;  // 10240, exact
  size_t required = (size_t)4 * NBHW * 4 + (size_t)16 * CAP * 8 + 64 + (size_t)nb * 2 * 4;
  if (ws_size < required) return;

  hipMemsetAsync(selbuf, 0, (size_t)NBHW * sizeof(float), stream);
  hipMemsetAsync(cnts, 0, 16 * sizeof(unsigned int), stream);

  k_warp<<<nb, 256, 0, stream>>>(score2, homo, w2buf, visbuf);
  dim3 g2(nb, 2);
  k_nms<<<g2, 256, 0, stream>>>(score1, w2buf, lists, cnts);
  k_topk<<<16, 1024, 0, stream>>>(lists, cnts, out, selbuf);
  k_blur_row<<<nb, 256, 0, stream>>>(selbuf, tmpbuf);
  k_loss<<<nb, 256, 0, stream>>>(score1, tmpbuf, visbuf, partials);
  k_final<<<1, 256, 0, stream>>>(partials, nb, out);
}

// Round 2
// 329.091 us; speedup vs baseline: 7.3334x; 7.3334x over previous
//
#include <hip/hip_runtime.h>

#define NB 8
#define NH 512
#define NW 640
#define NHW (NH*NW)
#define NBHW (NB*NHW)
#define TOPK 512
#define CAP 40960
#define PAD 8
#define CNT_STRIDE 64   // one counter per 256B cacheline

// Gaussian taps exp(-d^2/(2*0.5^2)) = exp(-2 d^2), unnormalized (matches outer(g1,g1))
__constant__ float GK[8] = {
  1.0f,
  0.1353352832366127f,
  3.3546262790251185e-4f,
  1.5229979744712628e-8f,
  1.2664165549094176e-14f,
  1.928749847963918e-22f,
  5.380186160021138e-32f,
  2.7487850079102147e-43f
};

__device__ __forceinline__ float bordered(const float* __restrict__ img, int b, int y, int x) {
  if (y < PAD || y >= NH - PAD || x < PAD || x >= NW - PAD) return 0.f;
  return img[b * NHW + y * NW + x];
}

__device__ __forceinline__ void corner(const float* __restrict__ img, float cx, float cy,
                                       float wgt, float& acc, float& vacc) {
  float valid = (cx >= 0.f && cx <= (float)(NW - 1) && cy >= 0.f && cy <= (float)(NH - 1)) ? 1.f : 0.f;
  float xc = fminf(fmaxf(cx, 0.f), (float)(NW - 1));
  float yc = fminf(fmaxf(cy, 0.f), (float)(NH - 1));
  int xi = (int)xc, yi = (int)yc;
  float g = img[yi * NW + xi] * valid;
  acc += wgt * g;
  vacc += wgt * valid;
}

// Pass 1: warp score2 by homo, border-filter -> w2; visibility mask -> vis
__global__ void k_warp(const float* __restrict__ score2, const float* __restrict__ homo,
                       float* __restrict__ w2, float* __restrict__ vis) {
  int gid = blockIdx.x * blockDim.x + threadIdx.x;
  if (gid >= NBHW) return;
  int b = gid / NHW;
  int p = gid % NHW;
  int y = p / NW, x = p % NW;
  const float* hm = homo + b * 9;
  float xf = (float)x, yf = (float)y;
  float X = hm[0] * xf + hm[1] * yf + hm[2];
  float Y = hm[3] * xf + hm[4] * yf + hm[5];
  float Z = hm[6] * xf + hm[7] * yf + hm[8];
  float x2 = X / Z, y2 = Y / Z;
  float x0 = floorf(x2), y0 = floorf(y2);
  float x1 = x0 + 1.f, y1 = y0 + 1.f;
  float wa = (x1 - x2) * (y1 - y2);
  float wb = (x2 - x0) * (y1 - y2);
  float wc = (x1 - x2) * (y2 - y0);
  float wd = (x2 - x0) * (y2 - y0);
  const float* img = score2 + b * NHW;
  float acc = 0.f, vacc = 0.f;
  corner(img, x0, y0, wa, acc, vacc);
  corner(img, x1, y0, wb, acc, vacc);
  corner(img, x0, y1, wc, acc, vacc);
  corner(img, x1, y1, wd, acc, vacc);
  bool inb = (y >= PAD && y < NH - PAD && x >= PAD && x < NW - PAD);
  w2[gid] = inb ? acc : 0.f;
  vis[gid] = (vacc > 0.f) ? 1.f : 0.f;
}

// Pass 2: 5x5 NMS; survivors pushed as 64-bit keys with block-aggregated atomics.
// key = (float_bits(val) << 32) | ~idx  -> descending key order == (val desc, idx asc)
__global__ void k_nms(const float* __restrict__ score1, const float* __restrict__ w2,
                      unsigned long long* __restrict__ lists, unsigned int* __restrict__ cnts) {
  int gid = blockIdx.x * blockDim.x + threadIdx.x;
  int src = blockIdx.y;
  const float* img = (src == 0) ? score1 : w2;
  int b = gid / NHW;           // block of 256 consecutive gids stays within one image
  int p = gid % NHW;
  int y = p / NW, x = p % NW;

  bool surv = false;
  float val = bordered(img, b, y, x);
  if (val > 0.f) {             // NMS_THRESH = 0
    float m = val;
    #pragma unroll
    for (int dy = -2; dy <= 2; ++dy) {
      #pragma unroll
      for (int dx = -2; dx <= 2; ++dx) {
        int yy = y + dy, xx = x + dx;
        if (yy < 0 || yy >= NH || xx < 0 || xx >= NW) continue;
        m = fmaxf(m, bordered(img, b, yy, xx));
      }
    }
    surv = (m == val);
  }

  __shared__ unsigned int s_cnt;
  __shared__ unsigned int s_base;
  if (threadIdx.x == 0) s_cnt = 0;
  __syncthreads();
  unsigned int local = 0;
  if (surv) local = atomicAdd(&s_cnt, 1u);   // LDS atomic, ~10 survivors/block
  __syncthreads();
  int li = src * NB + b;
  if (threadIdx.x == 0 && s_cnt > 0)
    s_base = atomicAdd(&cnts[li * CNT_STRIDE], s_cnt);  // one global atomic/block
  __syncthreads();
  if (surv) {
    unsigned int pos = s_base + local;
    if (pos < CAP) {
      unsigned long long key = ((unsigned long long)__float_as_uint(val) << 32)
                             | (unsigned long long)(~(unsigned int)p);
      lists[(size_t)li * CAP + pos] = key;
    }
  }
}

// Pass 3: exact top-512 per (source,image) via 64-bit MSB radix select + bitonic sort.
// src 0 -> write kp1 to out; src 1 -> scatter values into sel.
__global__ __launch_bounds__(1024) void k_topk(const unsigned long long* __restrict__ lists,
                                               const unsigned int* __restrict__ cnts,
                                               float* __restrict__ out, float* __restrict__ sel) {
  int li = blockIdx.x;           // 0..15
  int src = li >> 3, b = li & 7;
  unsigned int N = cnts[li * CNT_STRIDE]; if (N > CAP) N = CAP;
  const unsigned long long* list = lists + (size_t)li * CAP;
  __shared__ unsigned int hist[256];
  __shared__ unsigned long long keys[TOPK];
  __shared__ unsigned int scnt;
  __shared__ unsigned long long s_prefix;
  __shared__ int s_remaining;
  int tid = threadIdx.x, nt = blockDim.x;
  if (tid == 0) { s_prefix = 0ULL; s_remaining = TOPK; scnt = 0; }
  __syncthreads();

  unsigned long long threshold = 0ULL;
  if (N > TOPK) {
    for (int byte = 7; byte >= 0; --byte) {
      for (int i = tid; i < 256; i += nt) hist[i] = 0;
      __syncthreads();
      unsigned long long prefix = s_prefix;
      unsigned long long maskHigh = (byte == 7) ? 0ULL : (~0ULL << (unsigned)((byte + 1) * 8));
      int shift = byte * 8;
      for (unsigned int i = tid; i < N; i += nt) {
        unsigned long long k = list[i];
        if ((k & maskHigh) == prefix)
          atomicAdd(&hist[(unsigned int)(k >> shift) & 0xFFu], 1u);
      }
      __syncthreads();
      if (tid == 0) {
        int rem = s_remaining;
        unsigned int cum = 0;
        int chosen = 0;
        for (int bin = 255; bin >= 0; --bin) {
          unsigned int c = hist[bin];
          if (cum + c >= (unsigned int)rem) { chosen = bin; s_remaining = rem - (int)cum; break; }
          cum += c;
        }
        s_prefix = prefix | ((unsigned long long)chosen << shift);
      }
      __syncthreads();
    }
    threshold = s_prefix;
  }

  // collect keys >= threshold (exactly TOPK when N > TOPK; keys are unique)
  for (unsigned int i = tid; i < N; i += nt) {
    unsigned long long k = list[i];
    if (k >= threshold) {
      unsigned int pos = atomicAdd(&scnt, 1u);
      if (pos < TOPK) keys[pos] = k;
    }
  }
  __syncthreads();
  unsigned int M = scnt; if (M > TOPK) M = TOPK;
  for (unsigned int i = M + tid; i < TOPK; i += nt) keys[i] = 0ULL;
  __syncthreads();

  // bitonic sort descending, 512 elements
  for (int k2 = 2; k2 <= TOPK; k2 <<= 1) {
    for (int j = k2 >> 1; j > 0; j >>= 1) {
      for (int i = tid; i < TOPK; i += nt) {
        int ixj = i ^ j;
        if (ixj > i) {
          bool desc = ((i & k2) == 0);
          unsigned long long a = keys[i], c = keys[ixj];
          bool sw = desc ? (a < c) : (a > c);
          if (sw) { keys[i] = c; keys[ixj] = a; }
        }
      }
      __syncthreads();
    }
  }

  if (src == 0) {
    for (int r = tid; r < TOPK; r += nt) {
      unsigned long long k = keys[r];
      unsigned int idx = (k == 0ULL) ? 0u : ~(unsigned int)(k & 0xFFFFFFFFu);
      int yy = (int)(idx / NW), xx = (int)(idx % NW);
      out[1 + ((b * TOPK) + r) * 2 + 0] = (float)yy;
      out[1 + ((b * TOPK) + r) * 2 + 1] = (float)xx;
    }
  } else {
    for (unsigned int r = tid; r < M; r += nt) {
      unsigned long long k = keys[r];
      unsigned int idx = ~(unsigned int)(k & 0xFFFFFFFFu);
      sel[b * NHW + idx] = __uint_as_float((unsigned int)(k >> 32));
    }
  }
}

// Pass 4a: horizontal gaussian blur sel -> tmp
__global__ void k_blur_row(const float* __restrict__ sel, float* __restrict__ tmp) {
  int gid = blockIdx.x * blockDim.x + threadIdx.x;
  if (gid >= NBHW) return;
  int b = gid / NHW;
  int p = gid % NHW;
  int y = p / NW, x = p % NW;
  const float* row = sel + b * NHW + y * NW;
  float acc = 0.f;
  #pragma unroll
  for (int d = -7; d <= 7; ++d) {
    int xx = x + d;
    if (xx >= 0 && xx < NW) acc += GK[d < 0 ? -d : d] * row[xx];
  }
  tmp[gid] = acc;
}

// Pass 4b: vertical blur (gt) + masked squared-error partial sums
__global__ void k_loss(const float* __restrict__ score1, const float* __restrict__ tmp,
                       const float* __restrict__ vis, float* __restrict__ partials) {
  int gid = blockIdx.x * blockDim.x + threadIdx.x;
  float term = 0.f, vsum = 0.f;
  if (gid < NBHW) {
    int b = gid / NHW;
    int p = gid % NHW;
    int y = p / NW, x = p % NW;
    float gt = 0.f;
    #pragma unroll
    for (int d = -7; d <= 7; ++d) {
      int yy = y + d;
      if (yy >= 0 && yy < NH) gt += GK[d < 0 ? -d : d] * tmp[b * NHW + yy * NW + x];
    }
    float s1v = bordered(score1, b, y, x);
    float v = vis[gid];
    float df = s1v - gt;
    term = df * df * v;
    vsum = v;
  }
  __shared__ float shA[256];
  __shared__ float shB[256];
  int tid = threadIdx.x;
  shA[tid] = term; shB[tid] = vsum;
  __syncthreads();
  for (int s = 128; s > 0; s >>= 1) {
    if (tid < s) { shA[tid] += shA[tid + s]; shB[tid] += shB[tid + s]; }
    __syncthreads();
  }
  if (tid == 0) {
    partials[2 * blockIdx.x + 0] = shA[0];
    partials[2 * blockIdx.x + 1] = shB[0];
  }
}

// Pass 5: final deterministic reduction -> loss
__global__ void k_final(const float* __restrict__ partials, int np, float* __restrict__ out) {
  __shared__ double dA[256];
  __shared__ double dB[256];
  int tid = threadIdx.x;
  double s = 0.0, n = 0.0;
  for (int i = tid; i < np; i += 256) {
    s += (double)partials[2 * i + 0];
    n += (double)partials[2 * i + 1];
  }
  dA[tid] = s; dB[tid] = n;
  __syncthreads();
  for (int st = 128; st > 0; st >>= 1) {
    if (tid < st) { dA[tid] += dA[tid + st]; dB[tid] += dB[tid + st]; }
    __syncthreads();
  }
  if (tid == 0) out[0] = (float)(100.0 * dA[0] / dB[0]);
}

extern "C" void kernel_launch(void* const* d_in, const int* in_sizes, int n_in,
                              void* d_out, int out_size, void* d_ws, size_t ws_size,
                              hipStream_t stream) {
  const float* score1 = (const float*)d_in[0];
  const float* score2 = (const float*)d_in[1];
  const float* homo   = (const float*)d_in[2];
  float* out = (float*)d_out;

  // workspace layout
  float* w2buf  = (float*)d_ws;
  float* visbuf = w2buf + NBHW;
  float* selbuf = visbuf + NBHW;
  float* tmpbuf = selbuf + NBHW;
  unsigned long long* lists = (unsigned long long*)(tmpbuf + NBHW);
  unsigned int* cnts = (unsigned int*)(lists + (size_t)16 * CAP);
  float* partials = (float*)(cnts + 16 * CNT_STRIDE);

  const int nb = NBHW / 256;  // 10240, exact
  size_t required = (size_t)4 * NBHW * 4 + (size_t)16 * CAP * 8
                  + (size_t)16 * CNT_STRIDE * 4 + (size_t)nb * 2 * 4;
  if (ws_size < required) return;

  hipMemsetAsync(selbuf, 0, (size_t)NBHW * sizeof(float), stream);
  hipMemsetAsync(cnts, 0, 16 * CNT_STRIDE * sizeof(unsigned int), stream);

  k_warp<<<nb, 256, 0, stream>>>(score2, homo, w2buf, visbuf);
  dim3 g2(nb, 2);
  k_nms<<<g2, 256, 0, stream>>>(score1, w2buf, lists, cnts);
  k_topk<<<16, 1024, 0, stream>>>(lists, cnts, out, selbuf);
  k_blur_row<<<nb, 256, 0, stream>>>(selbuf, tmpbuf);
  k_loss<<<nb, 256, 0, stream>>>(score1, tmpbuf, visbuf, partials);
  k_final<<<1, 256, 0, stream>>>(partials, nb, out);
}

// Round 4
// 251.107 us; speedup vs baseline: 9.6109x; 1.3106x over previous
//
#include <hip/hip_runtime.h>

#define NB 8
#define NH 512
#define NW 640
#define NHW (NH*NW)
#define NBHW (NB*NHW)
#define TOPK 512
#define CAP 40960
#define PAD 8
#define CNT_STRIDE 64   // one counter per 256B cacheline

// NMS / loss tile geometry (block = 256 threads)
#define TW 64
#define TH 16

// Gaussian taps exp(-2 d^2); |d|>=3 taps are <=1.52e-8 -> negligible, radius 2 used
#define G0 1.0f
#define G1 0.1353352832366127f
#define G2 3.3546262790251185e-4f

__device__ __forceinline__ float bordered(const float* __restrict__ img, int b, int y, int x) {
  if (y < PAD || y >= NH - PAD || x < PAD || x >= NW - PAD) return 0.f;
  return img[b * NHW + y * NW + x];
}

__device__ __forceinline__ void corner(const float* __restrict__ img, float cx, float cy,
                                       float wgt, float& acc, float& vacc) {
  float valid = (cx >= 0.f && cx <= (float)(NW - 1) && cy >= 0.f && cy <= (float)(NH - 1)) ? 1.f : 0.f;
  float xc = fminf(fmaxf(cx, 0.f), (float)(NW - 1));
  float yc = fminf(fmaxf(cy, 0.f), (float)(NH - 1));
  int xi = (int)xc, yi = (int)yc;
  float g = img[yi * NW + xi] * valid;
  acc += wgt * g;
  vacc += wgt * valid;
}

// Fused warp + border-filter + 5x5 separable NMS.
// src==0: tile from score1. src==1: compute warped score2 on the fly (w2 never
// materialized), and write the visibility mask for the tile's core pixels.
// Survivors pushed as keys: (float_bits(val)<<32)|~idx -> desc key == (val desc, idx asc)
__global__ void k_nms2(const float* __restrict__ score1, const float* __restrict__ score2,
                       const float* __restrict__ homo, float* __restrict__ vis,
                       unsigned long long* __restrict__ lists, unsigned int* __restrict__ cnts) {
  int bx = blockIdx.x, by = blockIdx.y;
  int src = blockIdx.z >> 3, b = blockIdx.z & 7;
  int tid = threadIdx.x;

  __shared__ float in[TH + 4][TW + 4];     // 20 x 68
  __shared__ float hmax[TH + 4][TW];       // 20 x 64
  __shared__ unsigned int s_cnt;
  __shared__ unsigned int s_base;

  if (tid == 0) s_cnt = 0;

  float h0, h1, h2, h3, h4, h5, h6, h7, h8;
  if (src == 1) {
    const float* hm = homo + b * 9;
    h0 = hm[0]; h1 = hm[1]; h2 = hm[2];
    h3 = hm[3]; h4 = hm[4]; h5 = hm[5];
    h6 = hm[6]; h7 = hm[7]; h8 = hm[8];
  }

  // Phase 1: stage tile (+2 halo) into LDS, border-filtered.
  for (int i = tid; i < (TH + 4) * (TW + 4); i += 256) {
    int r = i / (TW + 4), c = i % (TW + 4);
    int gy = by * TH + r - 2, gx = bx * TW + c - 2;
    float v = 0.f;
    if (src == 0) {
      v = bordered(score1, b, gy, gx);
    } else {
      bool inb = (gy >= PAD && gy < NH - PAD && gx >= PAD && gx < NW - PAD);
      bool core = (r >= 2 && r < TH + 2 && c >= 2 && c < TW + 2);
      if (inb || core) {
        float xf = (float)gx, yf = (float)gy;
        float X = h0 * xf + h1 * yf + h2;
        float Y = h3 * xf + h4 * yf + h5;
        float Z = h6 * xf + h7 * yf + h8;
        float x2 = X / Z, y2 = Y / Z;
        float x0 = floorf(x2), y0 = floorf(y2);
        float x1 = x0 + 1.f, y1 = y0 + 1.f;
        float wa = (x1 - x2) * (y1 - y2);
        float wb = (x2 - x0) * (y1 - y2);
        float wc = (x1 - x2) * (y2 - y0);
        float wd = (x2 - x0) * (y2 - y0);
        const float* img = score2 + b * NHW;
        float acc = 0.f, vacc = 0.f;
        corner(img, x0, y0, wa, acc, vacc);
        corner(img, x1, y0, wb, acc, vacc);
        corner(img, x0, y1, wc, acc, vacc);
        corner(img, x1, y1, wd, acc, vacc);
        if (inb) v = acc;
        if (core) vis[b * NHW + gy * NW + gx] = (vacc > 0.f) ? 1.f : 0.f;
      }
    }
    in[r][c] = v;
  }
  __syncthreads();

  // Phase 2: horizontal 5-max
  for (int i = tid; i < (TH + 4) * TW; i += 256) {
    int r = i / TW, c = i % TW;
    float m = fmaxf(fmaxf(fmaxf(in[r][c], in[r][c + 1]), fmaxf(in[r][c + 2], in[r][c + 3])),
                    in[r][c + 4]);
    hmax[r][c] = m;
  }
  __syncthreads();

  // Phase 3: vertical 5-max + survivor detection (kept in registers)
  int nsv = 0;
  float svals[4];
  unsigned int sidx[4];
  #pragma unroll
  for (int it = 0; it < (TH * TW) / 256; ++it) {
    int i = it * 256 + tid;
    int r = i / TW, c = i % TW;
    float val = in[r + 2][c + 2];
    if (val > 0.f) {   // NMS_THRESH = 0
      float m = fmaxf(fmaxf(fmaxf(hmax[r][c], hmax[r + 1][c]), fmaxf(hmax[r + 2][c], hmax[r + 3][c])),
                      hmax[r + 4][c]);
      if (m == val) {
        int gy = by * TH + r, gx = bx * TW + c;
        svals[nsv] = val;
        sidx[nsv] = (unsigned int)(gy * NW + gx);
        ++nsv;
      }
    }
  }

  // Phase 4: block-aggregated push (one global atomic per block)
  unsigned int local = 0;
  if (nsv > 0) local = atomicAdd(&s_cnt, (unsigned int)nsv);
  __syncthreads();
  int li = src * NB + b;
  if (tid == 0 && s_cnt > 0) s_base = atomicAdd(&cnts[li * CNT_STRIDE], s_cnt);
  __syncthreads();
  for (int j = 0; j < nsv; ++j) {
    unsigned int pos = s_base + local + (unsigned int)j;
    if (pos < CAP) {
      unsigned long long key = ((unsigned long long)__float_as_uint(svals[j]) << 32)
                             | (unsigned long long)(~sidx[j]);
      lists[(size_t)li * CAP + pos] = key;
    }
  }
}

// Exact top-512 per (source,image): one 13-bit histogram pass + one collect pass
// + bitonic sort of <=2048 candidates by full 64-bit key. Byte-radix fallback for
// pathological distributions. src 0 -> kp1 to out; src 1 -> scatter vals into sel.
#define NT 1024
union TopkShared {
  unsigned int hist[8192];          // 32 KB
  unsigned long long sbuf[2048];    // 16 KB (aliases hist; hist dead before use)
};

__global__ __launch_bounds__(NT) void k_topk2(const unsigned long long* __restrict__ lists,
                                              const unsigned int* __restrict__ cnts,
                                              float* __restrict__ out, float* __restrict__ sel) {
  int li = blockIdx.x;             // 0..15
  int src = li >> 3, b = li & 7;
  unsigned int N = cnts[li * CNT_STRIDE]; if (N > CAP) N = CAP;
  const unsigned long long* list = lists + (size_t)li * CAP;

  __shared__ TopkShared u;
  __shared__ unsigned int scan[NT];
  __shared__ unsigned int s_chosen, s_total, s_nsel;
  __shared__ unsigned long long s_prefix;
  __shared__ int s_rem;
  int tid = threadIdx.x;

  bool lds_path = true;
  unsigned int chosen = 0;

  if (N > TOPK) {
    for (int i = tid; i < 8192; i += NT) u.hist[i] = 0;
    __syncthreads();
    for (unsigned int i = tid; i < N; i += NT)
      atomicAdd(&u.hist[(unsigned int)(list[i] >> 51)], 1u);
    __syncthreads();
    // descending prefix over 8192 bins: thread t covers bins [8191-8t .. 8184-8t]
    unsigned int psum = 0;
    int base = 8191 - 8 * tid;
    #pragma unroll
    for (int j = 0; j < 8; ++j) psum += u.hist[base - j];
    scan[tid] = psum;
    __syncthreads();
    for (int off = 1; off < NT; off <<= 1) {
      unsigned int v = (tid >= off) ? scan[tid - off] : 0u;
      __syncthreads();
      scan[tid] += v;
      __syncthreads();
    }
    unsigned int pre = scan[tid];
    unsigned int preprev = (tid == 0) ? 0u : scan[tid - 1];
    if (pre >= TOPK && preprev < TOPK) {
      unsigned int cum = preprev;
      for (int j = 0; j < 8; ++j) {
        unsigned int h = u.hist[base - j];
        if (cum + h >= TOPK) { s_chosen = (unsigned int)(base - j); s_total = cum + h; break; }
        cum += h;
      }
    }
    __syncthreads();
    chosen = s_chosen;
    if (s_total > 2048) lds_path = false;
  } else {
    if (tid == 0) s_total = N;
    __syncthreads();
    chosen = 0;
  }

  unsigned int total;
  if (lds_path) {
    if (tid == 0) s_nsel = 0;
    __syncthreads();
    for (unsigned int i = tid; i < N; i += NT) {
      unsigned long long k = list[i];
      if ((unsigned int)(k >> 51) >= chosen) {
        unsigned int pos = atomicAdd(&s_nsel, 1u);
        if (pos < 2048) u.sbuf[pos] = k;
      }
    }
    __syncthreads();
    total = s_nsel; if (total > 2048) total = 2048;
  } else {
    // fallback: classic MSB byte-radix (never taken for random inputs)
    if (tid == 0) { s_prefix = 0ULL; s_rem = TOPK; }
    __syncthreads();
    for (int byte = 7; byte >= 0; --byte) {
      for (int i = tid; i < 256; i += NT) u.hist[i] = 0;
      __syncthreads();
      unsigned long long prefix = s_prefix;
      unsigned long long maskHigh = (byte == 7) ? 0ULL : (~0ULL << (unsigned)((byte + 1) * 8));
      int shift = byte * 8;
      for (unsigned int i = tid; i < N; i += NT) {
        unsigned long long k = list[i];
        if ((k & maskHigh) == prefix)
          atomicAdd(&u.hist[(unsigned int)(k >> shift) & 0xFFu], 1u);
      }
      __syncthreads();
      if (tid == 0) {
        int rem = s_rem;
        unsigned int cum = 0;
        int ch = 0;
        for (int bin = 255; bin >= 0; --bin) {
          unsigned int c = u.hist[bin];
          if (cum + c >= (unsigned int)rem) { ch = bin; s_rem = rem - (int)cum; break; }
          cum += c;
        }
        s_prefix = prefix | ((unsigned long long)ch << shift);
      }
      __syncthreads();
    }
    unsigned long long thr = s_prefix;
    if (tid == 0) s_nsel = 0;
    __syncthreads();
    for (unsigned int i = tid; i < N; i += NT) {
      unsigned long long k = list[i];
      if (k >= thr) {
        unsigned int pos = atomicAdd(&s_nsel, 1u);
        if (pos < 2048) u.sbuf[pos] = k;
      }
    }
    __syncthreads();
    total = s_nsel; if (total > 2048) total = 2048;
  }

  // pad to S = max(512, next_pow2(total)), sort descending by full key
  unsigned int S = 512; while (S < total) S <<= 1;
  for (unsigned int i = tid; i < S; i += NT)
    if (i >= total) u.sbuf[i] = 0ULL;
  __syncthreads();

  for (unsigned int k2 = 2; k2 <= S; k2 <<= 1) {
    for (unsigned int j = k2 >> 1; j > 0; j >>= 1) {
      for (unsigned int i = tid; i < S; i += NT) {
        unsigned int ixj = i ^ j;
        if (ixj > i) {
          bool desc = ((i & k2) == 0);
          unsigned long long a = u.sbuf[i], c = u.sbuf[ixj];
          bool sw = desc ? (a < c) : (a > c);
          if (sw) { u.sbuf[i] = c; u.sbuf[ixj] = a; }
        }
      }
      __syncthreads();
    }
  }

  if (src == 0) {
    for (int r = tid; r < TOPK; r += NT) {
      unsigned long long k = u.sbuf[r];
      unsigned int idx = (k == 0ULL) ? 0u : ~(unsigned int)(k & 0xFFFFFFFFULL);
      int yy = (int)(idx / NW), xx = (int)(idx % NW);
      out[1 + ((b * TOPK) + r) * 2 + 0] = (float)yy;
      out[1 + ((b * TOPK) + r) * 2 + 1] = (float)xx;
    }
  } else {
    for (int r = tid; r < TOPK; r += NT) {
      unsigned long long k = u.sbuf[r];
      if (k != 0ULL) {
        unsigned int idx = ~(unsigned int)(k & 0xFFFFFFFFULL);
        sel[b * NHW + idx] = __uint_as_float((unsigned int)(k >> 32));
      }
    }
  }
}

// Fused separable gaussian (radius 2) + masked MSE partials -> fixed-point u64 atomics
__global__ void k_loss2(const float* __restrict__ score1, const float* __restrict__ sel,
                        const float* __restrict__ vis, unsigned long long* __restrict__ accum) {
  int bx = blockIdx.x, by = blockIdx.y, b = blockIdx.z;
  int tid = threadIdx.x;
  __shared__ float in2[TH + 4][TW + 4];
  __shared__ float hbuf[TH + 4][TW];
  __shared__ float shA[256];
  __shared__ unsigned int shI[256];

  for (int i = tid; i < (TH + 4) * (TW + 4); i += 256) {
    int r = i / (TW + 4), c = i % (TW + 4);
    int gy = by * TH + r - 2, gx = bx * TW + c - 2;
    in2[r][c] = (gy >= 0 && gy < NH && gx >= 0 && gx < NW) ? sel[b * NHW + gy * NW + gx] : 0.f;
  }
  __syncthreads();

  for (int i = tid; i < (TH + 4) * TW; i += 256) {
    int r = i / TW, c = i % TW;
    hbuf[r][c] = G2 * (in2[r][c] + in2[r][c + 4]) + G1 * (in2[r][c + 1] + in2[r][c + 3])
               + G0 * in2[r][c + 2];
  }
  __syncthreads();

  float tsum = 0.f;
  unsigned int vcnt = 0;
  #pragma unroll
  for (int it = 0; it < (TH * TW) / 256; ++it) {
    int i = it * 256 + tid;
    int r = i / TW, c = i % TW;
    int gy = by * TH + r, gx = bx * TW + c;
    float gt = G2 * (hbuf[r][c] + hbuf[r + 4][c]) + G1 * (hbuf[r + 1][c] + hbuf[r + 3][c])
             + G0 * hbuf[r + 2][c];
    float s1 = bordered(score1, b, gy, gx);
    float v = vis[b * NHW + gy * NW + gx];
    float d = s1 - gt;
    tsum += d * d * v;
    vcnt += (v > 0.f) ? 1u : 0u;
  }

  shA[tid] = tsum; shI[tid] = vcnt;
  __syncthreads();
  for (int s = 128; s > 0; s >>= 1) {
    if (tid < s) { shA[tid] += shA[tid + s]; shI[tid] += shI[tid + s]; }
    __syncthreads();
  }
  if (tid == 0) {
    // fixed-point: deterministic integer accumulation (order-independent)
    unsigned long long fp = (unsigned long long)((double)shA[0] * 4294967296.0);
    atomicAdd(&accum[0], fp);
    atomicAdd(&accum[1], (unsigned long long)shI[0]);
  }
}

__global__ void k_final2(const unsigned long long* __restrict__ accum, float* __restrict__ out) {
  if (threadIdx.x == 0) {
    double ts = (double)accum[0] / 4294967296.0;
    double n = (double)accum[1];
    out[0] = (float)(100.0 * ts / n);
  }
}

extern "C" void kernel_launch(void* const* d_in, const int* in_sizes, int n_in,
                              void* d_out, int out_size, void* d_ws, size_t ws_size,
                              hipStream_t stream) {
  const float* score1 = (const float*)d_in[0];
  const float* score2 = (const float*)d_in[1];
  const float* homo   = (const float*)d_in[2];
  float* out = (float*)d_out;

  // workspace layout
  float* visbuf = (float*)d_ws;
  float* selbuf = visbuf + NBHW;
  unsigned long long* lists = (unsigned long long*)(selbuf + NBHW);
  unsigned int* cnts = (unsigned int*)(lists + (size_t)16 * CAP);
  unsigned long long* accum = (unsigned long long*)(cnts + 16 * CNT_STRIDE);

  size_t required = (size_t)2 * NBHW * 4 + (size_t)16 * CAP * 8
                  + (size_t)16 * CNT_STRIDE * 4 + 16;
  if (ws_size < required) return;

  hipMemsetAsync(selbuf, 0, (size_t)NBHW * sizeof(float), stream);
  hipMemsetAsync(cnts, 0, 16 * CNT_STRIDE * sizeof(unsigned int) + 2 * sizeof(unsigned long long), stream);

  dim3 gnms(NW / TW, NH / TH, 16);    // 10 x 32 x 16
  k_nms2<<<gnms, 256, 0, stream>>>(score1, score2, homo, visbuf, lists, cnts);
  k_topk2<<<16, NT, 0, stream>>>(lists, cnts, out, selbuf);
  dim3 gloss(NW / TW, NH / TH, NB);   // 10 x 32 x 8
  k_loss2<<<gloss, 256, 0, stream>>>(score1, selbuf, visbuf, accum);
  k_final2<<<1, 64, 0, stream>>>(accum, out);
}

// Round 5
// 137.348 us; speedup vs baseline: 17.5712x; 1.8283x over previous
//
#include <hip/hip_runtime.h>

#define NB 8
#define NH 512
#define NW 640
#define NHW (NH*NW)
#define NBHW (NB*NHW)
#define TOPK 512
#define CAP 40960
#define PAD 8
#define CNT_STRIDE 64   // one counter per 256B cacheline
#define NBUCKET 32
#define GCAP 4096       // topk gather capacity (32 KB LDS)

// NMS / loss tile geometry (block = 256 threads)
#define TW 64
#define TH 16

// Gaussian taps exp(-2 d^2); |d|>=3 taps are <=1.52e-8 -> negligible, radius 2 used
#define G0 1.0f
#define G1 0.1353352832366127f
#define G2 3.3546262790251185e-4f

__device__ __forceinline__ float bordered(const float* __restrict__ img, int b, int y, int x) {
  if (y < PAD || y >= NH - PAD || x < PAD || x >= NW - PAD) return 0.f;
  return img[b * NHW + y * NW + x];
}

// Monotone (weakly increasing in val) bucket index, fine-grained near 1.0.
// val in (0,1): d = 0x3F800000 - bits(val) in (0, 0x3F800000) -> clz in [2,31].
__device__ __forceinline__ int vbucket(float val) {
  int d = 0x3F800000 - (int)__float_as_uint(val);
  if (d <= 0) return NBUCKET - 1;        // val >= 1.0
  int c = __clz(d);                       // 2..31
  return c > 30 ? 30 : c;
}

__device__ __forceinline__ void corner(const float* __restrict__ img, float cx, float cy,
                                       float wgt, float& acc, float& vacc) {
  float valid = (cx >= 0.f && cx <= (float)(NW - 1) && cy >= 0.f && cy <= (float)(NH - 1)) ? 1.f : 0.f;
  float xc = fminf(fmaxf(cx, 0.f), (float)(NW - 1));
  float yc = fminf(fmaxf(cy, 0.f), (float)(NH - 1));
  int xi = (int)xc, yi = (int)yc;
  float g = img[yi * NW + xi] * valid;
  acc += wgt * g;
  vacc += wgt * valid;
}

// Fused warp + border-filter + 5x5 separable NMS + per-bucket survivor counting.
// src==0: tile from score1. src==1: warp score2 on the fly; write vis mask.
// Survivors: flat list push (block-aggregated) + 32-bucket count update.
// key = (float_bits(val)<<32)|~idx -> desc key == (val desc, idx asc)
__global__ void k_nms2(const float* __restrict__ score1, const float* __restrict__ score2,
                       const float* __restrict__ homo, float* __restrict__ vis,
                       unsigned long long* __restrict__ lists, unsigned int* __restrict__ cbase) {
  int bx = blockIdx.x, by = blockIdx.y;
  int src = blockIdx.z >> 3, b = blockIdx.z & 7;
  int tid = threadIdx.x;

  __shared__ float in[TH + 4][TW + 4];     // 20 x 68
  __shared__ float hmax[TH + 4][TW];       // 20 x 64
  __shared__ unsigned int s_cnt;
  __shared__ unsigned int s_base;
  __shared__ unsigned int s_bh[NBUCKET];

  if (tid == 0) s_cnt = 0;
  if (tid < NBUCKET) s_bh[tid] = 0;

  float h0, h1, h2, h3, h4, h5, h6, h7, h8;
  if (src == 1) {
    const float* hm = homo + b * 9;
    h0 = hm[0]; h1 = hm[1]; h2 = hm[2];
    h3 = hm[3]; h4 = hm[4]; h5 = hm[5];
    h6 = hm[6]; h7 = hm[7]; h8 = hm[8];
  }

  // Phase 1: stage tile (+2 halo) into LDS, border-filtered.
  for (int i = tid; i < (TH + 4) * (TW + 4); i += 256) {
    int r = i / (TW + 4), c = i % (TW + 4);
    int gy = by * TH + r - 2, gx = bx * TW + c - 2;
    float v = 0.f;
    if (src == 0) {
      v = bordered(score1, b, gy, gx);
    } else {
      bool inb = (gy >= PAD && gy < NH - PAD && gx >= PAD && gx < NW - PAD);
      bool core = (r >= 2 && r < TH + 2 && c >= 2 && c < TW + 2);
      if (inb || core) {
        float xf = (float)gx, yf = (float)gy;
        float X = h0 * xf + h1 * yf + h2;
        float Y = h3 * xf + h4 * yf + h5;
        float Z = h6 * xf + h7 * yf + h8;
        float x2 = X / Z, y2 = Y / Z;
        float x0 = floorf(x2), y0 = floorf(y2);
        float x1 = x0 + 1.f, y1 = y0 + 1.f;
        float wa = (x1 - x2) * (y1 - y2);
        float wb = (x2 - x0) * (y1 - y2);
        float wc = (x1 - x2) * (y2 - y0);
        float wd = (x2 - x0) * (y2 - y0);
        const float* img = score2 + b * NHW;
        float acc = 0.f, vacc = 0.f;
        corner(img, x0, y0, wa, acc, vacc);
        corner(img, x1, y0, wb, acc, vacc);
        corner(img, x0, y1, wc, acc, vacc);
        corner(img, x1, y1, wd, acc, vacc);
        if (inb) v = acc;
        if (core) vis[b * NHW + gy * NW + gx] = (vacc > 0.f) ? 1.f : 0.f;
      }
    }
    in[r][c] = v;
  }
  __syncthreads();

  // Phase 2: horizontal 5-max
  for (int i = tid; i < (TH + 4) * TW; i += 256) {
    int r = i / TW, c = i % TW;
    float m = fmaxf(fmaxf(fmaxf(in[r][c], in[r][c + 1]), fmaxf(in[r][c + 2], in[r][c + 3])),
                    in[r][c + 4]);
    hmax[r][c] = m;
  }
  __syncthreads();

  // Phase 3: vertical 5-max + survivor detection (kept in registers)
  int nsv = 0;
  float svals[4];
  unsigned int sidx[4];
  #pragma unroll
  for (int it = 0; it < (TH * TW) / 256; ++it) {
    int i = it * 256 + tid;
    int r = i / TW, c = i % TW;
    float val = in[r + 2][c + 2];
    if (val > 0.f) {   // NMS_THRESH = 0
      float m = fmaxf(fmaxf(fmaxf(hmax[r][c], hmax[r + 1][c]), fmaxf(hmax[r + 2][c], hmax[r + 3][c])),
                      hmax[r + 4][c]);
      if (m == val) {
        int gy = by * TH + r, gx = bx * TW + c;
        svals[nsv] = val;
        sidx[nsv] = (unsigned int)(gy * NW + gx);
        ++nsv;
      }
    }
  }

  // Phase 4: block-aggregated push + bucket counts
  unsigned int local = 0;
  if (nsv > 0) local = atomicAdd(&s_cnt, (unsigned int)nsv);
  for (int j = 0; j < nsv; ++j) atomicAdd(&s_bh[vbucket(svals[j])], 1u);
  __syncthreads();
  int li = src * NB + b;
  if (tid == 0 && s_cnt > 0) s_base = atomicAdd(&cbase[li * CNT_STRIDE], s_cnt);
  if (tid < NBUCKET && s_bh[tid] > 0)
    atomicAdd(&cbase[(16 + li * NBUCKET + tid) * CNT_STRIDE], s_bh[tid]);
  __syncthreads();
  for (int j = 0; j < nsv; ++j) {
    unsigned int pos = s_base + local + (unsigned int)j;
    if (pos < CAP) {
      unsigned long long key = ((unsigned long long)__float_as_uint(svals[j]) << 32)
                             | (unsigned long long)(~sidx[j]);
      lists[(size_t)li * CAP + pos] = key;
    }
  }
}

// Exact top-512 per (source,image) using precomputed bucket counts:
// boundary bucket from counts -> ONE list scan gathering ~650 keys (ballot-
// aggregated push) -> bitonic sort by full 64-bit key -> outputs.
#define NT 1024
__global__ __launch_bounds__(NT) void k_topk3(const unsigned long long* __restrict__ lists,
                                              const unsigned int* __restrict__ cbase,
                                              float* __restrict__ out, float* __restrict__ sel) {
  int li = blockIdx.x;             // 0..15
  int src = li >> 3, b = li & 7;
  int tid = threadIdx.x;

  __shared__ unsigned long long sbuf[GCAP];
  __shared__ unsigned int s_bc[NBUCKET];
  __shared__ int s_bb;
  __shared__ unsigned int s_nsel;

  unsigned int N = cbase[li * CNT_STRIDE]; if (N > CAP) N = CAP;
  if (tid < NBUCKET) s_bc[tid] = cbase[(16 + li * NBUCKET + tid) * CNT_STRIDE];
  if (tid == 0) s_nsel = 0;
  __syncthreads();

  if (tid == 0) {
    unsigned int want = (N < TOPK) ? N : TOPK;
    int bb = NBUCKET;              // gather nothing if want == 0
    if (want > 0) {
      unsigned int cum = 0;
      for (int bk = NBUCKET - 1; bk >= 1; --bk) {
        cum += s_bc[bk];
        bb = bk;
        if (cum >= want) break;
      }
    }
    s_bb = bb;
  }
  __syncthreads();
  int bb = s_bb;

  // single gather scan with wave-aggregated LDS push
  const unsigned long long* list = lists + (size_t)li * CAP;
  int lane = tid & 63;
  for (unsigned int i = tid; i < N; i += NT) {
    unsigned long long k = list[i];
    float v = __uint_as_float((unsigned int)(k >> 32));
    bool pred = (vbucket(v) >= bb);
    unsigned long long mask = __ballot(pred);
    if (mask) {
      int leader = __ffsll((long long)mask) - 1;
      unsigned int cnt = (unsigned int)__popcll(mask);
      unsigned int bp = 0;
      if (lane == leader) bp = atomicAdd(&s_nsel, cnt);
      bp = __shfl(bp, leader, 64);
      if (pred) {
        unsigned int pos = bp + (unsigned int)__popcll(mask & ((1ULL << lane) - 1ULL));
        if (pos < GCAP) sbuf[pos] = k;
      }
    }
  }
  __syncthreads();
  unsigned int total = s_nsel; if (total > GCAP) total = GCAP;

  // pad to S = max(512, next_pow2(total)) <= GCAP, sort descending by full key
  unsigned int S = 512; while (S < total) S <<= 1;
  for (unsigned int i = tid; i < S; i += NT)
    if (i >= total) sbuf[i] = 0ULL;
  __syncthreads();

  for (unsigned int k2 = 2; k2 <= S; k2 <<= 1) {
    for (unsigned int j = k2 >> 1; j > 0; j >>= 1) {
      for (unsigned int i = tid; i < S; i += NT) {
        unsigned int ixj = i ^ j;
        if (ixj > i) {
          bool desc = ((i & k2) == 0);
          unsigned long long a = sbuf[i], c = sbuf[ixj];
          bool sw = desc ? (a < c) : (a > c);
          if (sw) { sbuf[i] = c; sbuf[ixj] = a; }
        }
      }
      __syncthreads();
    }
  }

  if (src == 0) {
    for (int r = tid; r < TOPK; r += NT) {
      unsigned long long k = sbuf[r];
      unsigned int idx = (k == 0ULL) ? 0u : ~(unsigned int)(k & 0xFFFFFFFFULL);
      int yy = (int)(idx / NW), xx = (int)(idx % NW);
      out[1 + ((b * TOPK) + r) * 2 + 0] = (float)yy;
      out[1 + ((b * TOPK) + r) * 2 + 1] = (float)xx;
    }
  } else {
    for (int r = tid; r < TOPK; r += NT) {
      unsigned long long k = sbuf[r];
      if (k != 0ULL) {
        unsigned int idx = ~(unsigned int)(k & 0xFFFFFFFFULL);
        sel[b * NHW + idx] = __uint_as_float((unsigned int)(k >> 32));
      }
    }
  }
}

// Fused separable gaussian (radius 2) + masked MSE partials -> fixed-point u64 atomics
__global__ void k_loss2(const float* __restrict__ score1, const float* __restrict__ sel,
                        const float* __restrict__ vis, unsigned long long* __restrict__ accum) {
  int bx = blockIdx.x, by = blockIdx.y, b = blockIdx.z;
  int tid = threadIdx.x;
  __shared__ float in2[TH + 4][TW + 4];
  __shared__ float hbuf[TH + 4][TW];
  __shared__ float shA[256];
  __shared__ unsigned int shI[256];

  for (int i = tid; i < (TH + 4) * (TW + 4); i += 256) {
    int r = i / (TW + 4), c = i % (TW + 4);
    int gy = by * TH + r - 2, gx = bx * TW + c - 2;
    in2[r][c] = (gy >= 0 && gy < NH && gx >= 0 && gx < NW) ? sel[b * NHW + gy * NW + gx] : 0.f;
  }
  __syncthreads();

  for (int i = tid; i < (TH + 4) * TW; i += 256) {
    int r = i / TW, c = i % TW;
    hbuf[r][c] = G2 * (in2[r][c] + in2[r][c + 4]) + G1 * (in2[r][c + 1] + in2[r][c + 3])
               + G0 * in2[r][c + 2];
  }
  __syncthreads();

  float tsum = 0.f;
  unsigned int vcnt = 0;
  #pragma unroll
  for (int it = 0; it < (TH * TW) / 256; ++it) {
    int i = it * 256 + tid;
    int r = i / TW, c = i % TW;
    int gy = by * TH + r, gx = bx * TW + c;
    float gt = G2 * (hbuf[r][c] + hbuf[r + 4][c]) + G1 * (hbuf[r + 1][c] + hbuf[r + 3][c])
             + G0 * hbuf[r + 2][c];
    float s1 = bordered(score1, b, gy, gx);
    float v = vis[b * NHW + gy * NW + gx];
    float d = s1 - gt;
    tsum += d * d * v;
    vcnt += (v > 0.f) ? 1u : 0u;
  }

  shA[tid] = tsum; shI[tid] = vcnt;
  __syncthreads();
  for (int s = 128; s > 0; s >>= 1) {
    if (tid < s) { shA[tid] += shA[tid + s]; shI[tid] += shI[tid + s]; }
    __syncthreads();
  }
  if (tid == 0) {
    // fixed-point: deterministic integer accumulation (order-independent)
    unsigned long long fp = (unsigned long long)((double)shA[0] * 4294967296.0);
    atomicAdd(&accum[0], fp);
    atomicAdd(&accum[1], (unsigned long long)shI[0]);
  }
}

__global__ void k_final2(const unsigned long long* __restrict__ accum, float* __restrict__ out) {
  if (threadIdx.x == 0) {
    double ts = (double)accum[0] / 4294967296.0;
    double n = (double)accum[1];
    out[0] = (float)(100.0 * ts / n);
  }
}

extern "C" void kernel_launch(void* const* d_in, const int* in_sizes, int n_in,
                              void* d_out, int out_size, void* d_ws, size_t ws_size,
                              hipStream_t stream) {
  const float* score1 = (const float*)d_in[0];
  const float* score2 = (const float*)d_in[1];
  const float* homo   = (const float*)d_in[2];
  float* out = (float*)d_out;

  // workspace layout
  float* visbuf = (float*)d_ws;
  float* selbuf = visbuf + NBHW;
  unsigned long long* lists = (unsigned long long*)(selbuf + NBHW);
  unsigned int* cbase = (unsigned int*)(lists + (size_t)16 * CAP);
  // cbase: [0..15]*CNT_STRIDE totals; [(16 + li*32 + b)]*CNT_STRIDE bucket counts
  const int NCNT = (16 + 16 * NBUCKET) * CNT_STRIDE;   // 528*64 u32
  unsigned long long* accum = (unsigned long long*)(cbase + NCNT);

  size_t required = (size_t)2 * NBHW * 4 + (size_t)16 * CAP * 8
                  + (size_t)NCNT * 4 + 16;
  if (ws_size < required) return;

  hipMemsetAsync(selbuf, 0, (size_t)NBHW * sizeof(float), stream);
  hipMemsetAsync(cbase, 0, (size_t)NCNT * 4 + 16, stream);

  dim3 gnms(NW / TW, NH / TH, 16);    // 10 x 32 x 16
  k_nms2<<<gnms, 256, 0, stream>>>(score1, score2, homo, visbuf, lists, cbase);
  k_topk3<<<16, NT, 0, stream>>>(lists, cbase, out, selbuf);
  dim3 gloss(NW / TW, NH / TH, NB);   // 10 x 32 x 8
  k_loss2<<<gloss, 256, 0, stream>>>(score1, selbuf, visbuf, accum);
  k_final2<<<1, 64, 0, stream>>>(accum, out);
}